// Round 1
// baseline (143.059 us; speedup 1.0000x reference)
//
#include <hip/hip_runtime.h>
#include <hip/hip_bf16.h>
#include <float.h>

// Problem constants (from reference): S=8192 tokens, E=64 experts, C=256 capacity
constexpr int S = 8192;
constexpr int E = 64;
constexpr int C = 256;
constexpr int K1_BLOCKS = 256;              // compute kernel blocks
constexpr int ROWS_PER_BLOCK = S / K1_BLOCKS; // 32

// ---------------------------------------------------------------------------
// Kernel 1: zero the entire output buffer (l_aux slot + combine_weights).
// out_size = 1 + S*E*C = 134217729 floats. float4 over first 134217728, tail scalar.
// ---------------------------------------------------------------------------
__global__ void zero_kernel(float4* __restrict__ out4, size_t n4, float* __restrict__ out_tail) {
    size_t i = (size_t)blockIdx.x * blockDim.x + threadIdx.x;
    size_t stride = (size_t)gridDim.x * blockDim.x;
    const float4 z = make_float4(0.f, 0.f, 0.f, 0.f);
    for (; i < n4; i += stride) out4[i] = z;
    if (blockIdx.x == 0 && threadIdx.x == 0) *out_tail = 0.f;
}

// ---------------------------------------------------------------------------
// Kernel 2: per-row softmax + top-2 gate extraction + scatter + l_aux partials.
// One wave (64 lanes) per row; lane e owns expert e. Block = 4 waves.
// Each block handles ROWS_PER_BLOCK consecutive rows, writes 128 partial
// floats (me-sum[64], ce-sum[64]) to ws at block slot (deterministic, no atomics).
// ---------------------------------------------------------------------------
__global__ __launch_bounds__(256) void compute_kernel(
        const float* __restrict__ logits,
        const float* __restrict__ mask1,
        const float* __restrict__ mask2,
        const float* __restrict__ loc1,
        const float* __restrict__ loc2,
        float* __restrict__ out,
        float* __restrict__ ws_partials) {
    __shared__ float me_s[4][64];
    __shared__ float ce_s[4][64];

    const int lane = threadIdx.x & 63;
    const int wave = threadIdx.x >> 6;
    const int row0 = blockIdx.x * ROWS_PER_BLOCK;

    float me_acc = 0.f;   // sum over this wave's rows of gates[s, lane]
    float ce_acc = 0.f;   // sum over this wave's rows of mask1[s, lane]

    for (int r = wave; r < ROWS_PER_BLOCK; r += 4) {
        const int s = row0 + r;
        // --- softmax over E=64 (one lane per expert) ---
        float x = logits[(size_t)s * E + lane];
        float mx = x;
        #pragma unroll
        for (int off = 32; off > 0; off >>= 1) mx = fmaxf(mx, __shfl_xor(mx, off));
        float ex = __expf(x - mx);
        float sum = ex;
        #pragma unroll
        for (int off = 32; off > 0; off >>= 1) sum += __shfl_xor(sum, off);
        const float g = ex / sum;

        const float m1v = mask1[(size_t)s * E + lane];
        const float m2v = mask2[(size_t)s * E + lane];
        me_acc += g;
        ce_acc += m1v;

        // gate values and expert indices via wave reduction over one-hot masks
        float g1 = g * m1v, g2 = g * m2v;
        float e1f = m1v * (float)lane, e2f = m2v * (float)lane;
        #pragma unroll
        for (int off = 32; off > 0; off >>= 1) {
            g1  += __shfl_xor(g1,  off);
            g2  += __shfl_xor(g2,  off);
            e1f += __shfl_xor(e1f, off);
            e2f += __shfl_xor(e2f, off);
        }

        // capacity slots: one-hot rows of length C=256; each lane scans 4 (float4)
        const float4 l1v = *reinterpret_cast<const float4*>(loc1 + (size_t)s * C + lane * 4);
        const float4 l2v = *reinterpret_cast<const float4*>(loc2 + (size_t)s * C + lane * 4);
        float c1f = 0.f, c2f = 0.f;
        const float base_idx = (float)(lane * 4);
        if (l1v.x > 0.5f) c1f = base_idx + 0.f;
        if (l1v.y > 0.5f) c1f = base_idx + 1.f;
        if (l1v.z > 0.5f) c1f = base_idx + 2.f;
        if (l1v.w > 0.5f) c1f = base_idx + 3.f;
        if (l2v.x > 0.5f) c2f = base_idx + 0.f;
        if (l2v.y > 0.5f) c2f = base_idx + 1.f;
        if (l2v.z > 0.5f) c2f = base_idx + 2.f;
        if (l2v.w > 0.5f) c2f = base_idx + 3.f;
        #pragma unroll
        for (int off = 32; off > 0; off >>= 1) {
            c1f = fmaxf(c1f, __shfl_xor(c1f, off));
            c2f = fmaxf(c2f, __shfl_xor(c2f, off));
        }

        if (lane == 0) {
            float denom = g1 + g2;
            denom = fmaxf(denom, FLT_EPSILON);  // 1.1920929e-07
            const float w1 = g1 / denom;
            const float w2 = g2 / denom;
            const int e1 = (int)(e1f + 0.5f);
            const int e2 = (int)(e2f + 0.5f);
            const int c1 = (int)(c1f + 0.5f);
            const int c2 = (int)(c2f + 0.5f);
            const size_t base = 1 + (size_t)s * (E * C);
            out[base + (size_t)e1 * C + c1] = w1;
            out[base + (size_t)e2 * C + c2] = w2;
        }
    }

    me_s[wave][lane] = me_acc;
    ce_s[wave][lane] = ce_acc;
    __syncthreads();
    if (threadIdx.x < 64) {
        const float me_b = me_s[0][lane] + me_s[1][lane] + me_s[2][lane] + me_s[3][lane];
        const float ce_b = ce_s[0][lane] + ce_s[1][lane] + ce_s[2][lane] + ce_s[3][lane];
        ws_partials[(size_t)blockIdx.x * 128 + lane]      = me_b;
        ws_partials[(size_t)blockIdx.x * 128 + 64 + lane] = ce_b;
    }
}

// ---------------------------------------------------------------------------
// Kernel 3: final l_aux = E * sum_e (me[e] * ce[e]) / S^2, written to out[0].
// ---------------------------------------------------------------------------
__global__ void laux_kernel(const float* __restrict__ ws_partials, float* __restrict__ out) {
    const int lane = threadIdx.x;  // 64 threads
    float me = 0.f, ce = 0.f;
    for (int b = 0; b < K1_BLOCKS; ++b) {
        me += ws_partials[(size_t)b * 128 + lane];
        ce += ws_partials[(size_t)b * 128 + 64 + lane];
    }
    float prod = me * ce;
    #pragma unroll
    for (int off = 32; off > 0; off >>= 1) prod += __shfl_xor(prod, off);
    if (lane == 0) {
        out[0] = prod * (float)E / ((float)S * (float)S);
    }
}

extern "C" void kernel_launch(void* const* d_in, const int* in_sizes, int n_in,
                              void* d_out, int out_size, void* d_ws, size_t ws_size,
                              hipStream_t stream) {
    const float* logits = (const float*)d_in[0];
    const float* mask1  = (const float*)d_in[1];
    const float* mask2  = (const float*)d_in[2];
    const float* loc1   = (const float*)d_in[3];
    const float* loc2   = (const float*)d_in[4];
    float* out = (float*)d_out;
    float* ws  = (float*)d_ws;

    // 1) zero full output (134217729 floats = 33554432 float4 + 1 tail)
    const size_t n4 = (size_t)(out_size - 1) / 4;  // 33554432
    zero_kernel<<<2048, 256, 0, stream>>>((float4*)out, n4, out + (size_t)out_size - 1);

    // 2) per-row compute + scatter + partials
    compute_kernel<<<K1_BLOCKS, 256, 0, stream>>>(logits, mask1, mask2, loc1, loc2, out, ws);

    // 3) l_aux reduce
    laux_kernel<<<1, 64, 0, stream>>>(ws, out);
}

// Round 2
// 131.079 us; speedup vs baseline: 1.0914x; 1.0914x over previous
//
#include <hip/hip_runtime.h>
#include <hip/hip_bf16.h>
#include <float.h>

// Problem constants: S=8192 tokens, E=64 experts, C=256 capacity
constexpr int S = 8192;
constexpr int E = 64;
constexpr int C = 256;
constexpr int A_BLOCKS = 512;                       // compute kernel blocks (4 waves each)
constexpr int ROWS_PER_WAVE = S / (A_BLOCKS * 4);   // 4

// ---------------------------------------------------------------------------
// Kernel A: per-row softmax + top-2 gate extraction + scatter into (pre-zeroed)
// out + per-block l_aux partials. One wave (64 lanes) per row; lane = expert.
// 512 blocks x 256 threads = 2048 waves, 4 rows per wave.
// Only the two softmax reductions use shuffle chains; expert/capacity indices
// come from single ballots (one-hot inputs), gate values from one __shfl.
// ---------------------------------------------------------------------------
__global__ __launch_bounds__(256) void compute_kernel(
        const float* __restrict__ logits,
        const float* __restrict__ mask1,
        const float* __restrict__ mask2,
        const float* __restrict__ loc1,
        const float* __restrict__ loc2,
        float* __restrict__ out,
        float* __restrict__ ws_partials) {
    __shared__ float me_s[4][64];
    __shared__ float ce_s[4][64];

    const int lane = threadIdx.x & 63;
    const int wave = threadIdx.x >> 6;

    float me_acc = 0.f;   // sum over rows of gates[s, lane]
    float ce_acc = 0.f;   // sum over rows of mask1[s, lane]

    #pragma unroll
    for (int r = 0; r < ROWS_PER_WAVE; ++r) {
        const int s = blockIdx.x * (4 * ROWS_PER_WAVE) + wave * ROWS_PER_WAVE + r;

        // --- softmax over E=64 (one lane per expert) ---
        const float x = logits[(size_t)s * E + lane];
        float mx = x;
        #pragma unroll
        for (int off = 32; off > 0; off >>= 1) mx = fmaxf(mx, __shfl_xor(mx, off));
        const float ex = __expf(x - mx);
        float sum = ex;
        #pragma unroll
        for (int off = 32; off > 0; off >>= 1) sum += __shfl_xor(sum, off);
        const float g = ex / sum;

        const float m1v = mask1[(size_t)s * E + lane];
        const float m2v = mask2[(size_t)s * E + lane];
        me_acc += g;
        ce_acc += m1v;

        // expert indices via ballot over the one-hot masks (exactly one bit set)
        const unsigned long long b1 = __ballot(m1v > 0.5f);
        const unsigned long long b2 = __ballot(m2v > 0.5f);
        const int e1 = __ffsll(b1) - 1;
        const int e2 = __ffsll(b2) - 1;
        const float g1 = __shfl(g, e1);
        const float g2 = __shfl(g, e2);

        // capacity slots: one-hot rows of length C=256; lane scans 4 via float4
        const float4 l1v = *reinterpret_cast<const float4*>(loc1 + (size_t)s * C + lane * 4);
        const float4 l2v = *reinterpret_cast<const float4*>(loc2 + (size_t)s * C + lane * 4);
        const int bm1 = (l1v.x > 0.5f ? 1 : 0) | (l1v.y > 0.5f ? 2 : 0) |
                        (l1v.z > 0.5f ? 4 : 0) | (l1v.w > 0.5f ? 8 : 0);
        const int bm2 = (l2v.x > 0.5f ? 1 : 0) | (l2v.y > 0.5f ? 2 : 0) |
                        (l2v.z > 0.5f ? 4 : 0) | (l2v.w > 0.5f ? 8 : 0);
        const int L1 = __ffsll(__ballot(bm1 != 0)) - 1;   // which lane holds the slot
        const int L2 = __ffsll(__ballot(bm2 != 0)) - 1;
        const int sub1 = __ffs(__shfl(bm1, L1)) - 1;       // which of its 4
        const int sub2 = __ffs(__shfl(bm2, L2)) - 1;

        if (lane == 0) {
            const int c1 = L1 * 4 + sub1;
            const int c2 = L2 * 4 + sub2;
            const float denom = fmaxf(g1 + g2, FLT_EPSILON);
            const size_t base = 1 + (size_t)s * (E * C);
            out[base + (size_t)e1 * C + c1] = g1 / denom;
            out[base + (size_t)e2 * C + c2] = g2 / denom;
        }
    }

    me_s[wave][lane] = me_acc;
    ce_s[wave][lane] = ce_acc;
    __syncthreads();
    if (threadIdx.x < 64) {
        const float me_b = me_s[0][lane] + me_s[1][lane] + me_s[2][lane] + me_s[3][lane];
        const float ce_b = ce_s[0][lane] + ce_s[1][lane] + ce_s[2][lane] + ce_s[3][lane];
        ws_partials[(size_t)blockIdx.x * 128 + lane]      = me_b;
        ws_partials[(size_t)blockIdx.x * 128 + 64 + lane] = ce_b;
    }
}

// ---------------------------------------------------------------------------
// Kernel C: l_aux = (E/S^2) * sum_e me_sum[e]*ce_sum[e], written to out[0].
// 256 threads: thread (q, e) sums blocks b ≡ q (mod 4); LDS combine.
// ---------------------------------------------------------------------------
__global__ __launch_bounds__(256) void laux_kernel(const float* __restrict__ ws_partials,
                                                   float* __restrict__ out) {
    __shared__ float mes[4][64];
    __shared__ float ces[4][64];
    const int e = threadIdx.x & 63;
    const int q = threadIdx.x >> 6;
    float me = 0.f, ce = 0.f;
    for (int b = q; b < A_BLOCKS; b += 4) {
        me += ws_partials[(size_t)b * 128 + e];
        ce += ws_partials[(size_t)b * 128 + 64 + e];
    }
    mes[q][e] = me;
    ces[q][e] = ce;
    __syncthreads();
    if (threadIdx.x < 64) {
        const float m = mes[0][e] + mes[1][e] + mes[2][e] + mes[3][e];
        const float c = ces[0][e] + ces[1][e] + ces[2][e] + ces[3][e];
        float prod = m * c;
        #pragma unroll
        for (int off = 32; off > 0; off >>= 1) prod += __shfl_xor(prod, off);
        if (e == 0) out[0] = prod * (float)E / ((float)S * (float)S);
    }
}

extern "C" void kernel_launch(void* const* d_in, const int* in_sizes, int n_in,
                              void* d_out, int out_size, void* d_ws, size_t ws_size,
                              hipStream_t stream) {
    const float* logits = (const float*)d_in[0];
    const float* mask1  = (const float*)d_in[1];
    const float* mask2  = (const float*)d_in[2];
    const float* loc1   = (const float*)d_in[3];
    const float* loc2   = (const float*)d_in[4];
    float* out = (float*)d_out;
    float* ws  = (float*)d_ws;

    // 1) zero full output via the runtime's optimized fill path (graph memset node)
    hipMemsetAsync(out, 0, (size_t)out_size * sizeof(float), stream);

    // 2) per-row compute + scatter + l_aux partials
    compute_kernel<<<A_BLOCKS, 256, 0, stream>>>(logits, mask1, mask2, loc1, loc2, out, ws);

    // 3) l_aux reduce
    laux_kernel<<<1, 256, 0, stream>>>(ws, out);
}